// Round 5
// baseline (255.840 us; speedup 1.0000x reference)
//
#include <hip/hip_runtime.h>
#include <cstdint>

#define BB 4
#define NN 4096
#define CC 256

typedef __attribute__((ext_vector_type(8))) short bf16x8;
typedef __attribute__((ext_vector_type(4))) short bf16x4;
typedef __attribute__((ext_vector_type(4))) float f32x4;
typedef unsigned int u32;
typedef __attribute__((ext_vector_type(4))) u32 u32x4;

#define MFMA_BF16(a, b, c) __builtin_amdgcn_mfma_f32_16x16x32_bf16((a), (b), (c), 0, 0, 0)
#define MFMA_FP8(a, b, c)  __builtin_amdgcn_mfma_f32_16x16x32_fp8_fp8((a), (b), (c), 0, 0, 0)

// gfx9 s_waitcnt immediate: vmcnt[3:0]+[15:14], expcnt[6:4], lgkmcnt[11:8]
#define WAITCNT(vm, xp, lgkm) (((vm) & 0xF) | (((vm) >> 4) << 14) | ((xp) << 4) | ((lgkm) << 8))

__device__ __forceinline__ unsigned short f2bf(float f) {
  union { float f; unsigned u; } v; v.f = f;
  unsigned r = v.u + 0x7fffu + ((v.u >> 16) & 1u);
  return (unsigned short)(r >> 16);
}
__device__ __forceinline__ float bf2f(unsigned short h) {
  union { unsigned u; float f; } v; v.u = ((unsigned)h) << 16;
  return v.f;
}
// pack 4 f32 -> 4 fp8 e4m3 (OCP) in one dword, byte order a,b,c,d
__device__ __forceinline__ u32 pk4_fp8(float a, float b, float c, float d) {
  u32 v = (u32)__builtin_amdgcn_cvt_pk_fp8_f32(a, b, 0, false);
  v = (u32)__builtin_amdgcn_cvt_pk_fp8_f32(c, d, (int)v, true);
  return v;
}

typedef __attribute__((address_space(3))) unsigned int lds_u32;
typedef __attribute__((address_space(1))) unsigned int glb_u32;

// async global->LDS, 16B per lane; LDS dest = wave-uniform base + lane*16
__device__ __forceinline__ void async_cp16(const void* g, void* l) {
  __builtin_amdgcn_global_load_lds((const glb_u32*)g,
                                   (lds_u32*)(unsigned)(unsigned long long)l,
                                   16, 0, 0);
}

// ---------------- W transpose: Wt[z][d][c] = W_z[c][d] as bf16 ----------------
__global__ __launch_bounds__(256) void transpose_w(const float* __restrict__ Wq,
                                                   const float* __restrict__ Wk,
                                                   const float* __restrict__ Wv,
                                                   unsigned short* __restrict__ Wt) {
  __shared__ float sT[64 * 65];
  int blk = blockIdx.x;            // 48 = 3 * 16
  int z = blk / 16, tl = blk % 16;
  int c0 = (tl >> 2) * 64, d0 = (tl & 3) * 64;
  const float* W = (z == 0) ? Wq : ((z == 1) ? Wk : Wv);
  #pragma unroll
  for (int i = 0; i < 16; ++i) {
    int e = i * 256 + threadIdx.x;
    int c = e >> 6, d = e & 63;
    sT[c * 65 + d] = W[(size_t)(c0 + c) * CC + d0 + d];
  }
  __syncthreads();
  #pragma unroll
  for (int i = 0; i < 16; ++i) {
    int e = i * 256 + threadIdx.x;
    int d = e >> 6, c = e & 63;
    Wt[(size_t)z * 65536 + (size_t)(d0 + d) * CC + c0 + c] = f2bf(sT[c * 65 + d]);
  }
}

// ---------------- instance-norm stats ----------------
__global__ __launch_bounds__(256) void stats_partial(const float* __restrict__ content,
                                                     const float* __restrict__ style,
                                                     float* __restrict__ sums) {
  int blk = blockIdx.x;                 // 1024 blocks: [t:2][b:4][chunk:128]
  int t = blk >> 9, b = (blk >> 7) & 3, chunk = blk & 127;
  const float* X = t ? style : content;
  int c = threadIdx.x;
  const float* base = X + ((size_t)b * NN + (size_t)chunk * 32) * CC + c;
  float s = 0.f, ss = 0.f;
  #pragma unroll 8
  for (int r = 0; r < 32; ++r) {
    float x = base[(size_t)r * CC];
    s += x; ss += x * x;
  }
  atomicAdd(&sums[((t * 2 + 0) * BB + b) * CC + c], s);
  atomicAdd(&sums[((t * 2 + 1) * BB + b) * CC + c], ss);
}

__global__ __launch_bounds__(256) void stats_finalize(const float* __restrict__ sums,
                                                      float* __restrict__ stats) {
  int i = blockIdx.x * 256 + threadIdx.x;   // 2048 = 2*B*C
  int t = i >> 10, bc = i & 1023;
  float s = sums[(t * 2 + 0) * 1024 + bc];
  float ss = sums[(t * 2 + 1) * 1024 + bc];
  float m = s * (1.0f / NN);
  float var = ss * (1.0f / NN) - m * m;
  stats[(t * 2 + 0) * 1024 + bc] = m;
  stats[(t * 2 + 1) * 1024 + bc] = rsqrtf(var + 1e-5f);
}

// ---------------- QKV: x(normed) @ W + b -> fp8 Q/K (l2norm) and fp8 V/V^2 transposed ----------------
__global__ __launch_bounds__(256, 2) void qkv_kernel(
    const float* __restrict__ content, const float* __restrict__ style,
    const unsigned short* __restrict__ Wt,
    const float* __restrict__ bq, const float* __restrict__ bk, const float* __restrict__ bv,
    const float* __restrict__ stats,
    unsigned char* __restrict__ Qn, unsigned char* __restrict__ Kn,
    unsigned char* __restrict__ Vct) {
  __shared__ unsigned short sX[64 * 256];    // 32 KB, x-hat [row][c], swizzled (32 chunks/row)
  __shared__ unsigned short sWOT[256 * 64];  // 32 KB, sW [d][k] swizzled; V-epilogue alias sOT [d][row]
  __shared__ float sSq[64];

  int tid = threadIdx.x;
  int wid = tid >> 6, lane = tid & 63, quad = lane >> 4, l16 = lane & 15;
  int uwid = __builtin_amdgcn_readfirstlane(wid);
  int tileid = blockIdx.x;      // 0..255 over B*N/64
  int z = blockIdx.y;           // 0=Q 1=K 2=V
  int gr0 = tileid * 64;        // global row over B*N
  int b = gr0 >> 12;

  const float* X = (z == 0) ? content : style;
  int statt = (z == 0) ? 0 : 1;
  const float* mean = stats + ((statt * 2 + 0) * BB + b) * CC;
  const float* rstd = stats + ((statt * 2 + 1) * BB + b) * CC;
  bool donorm = (z < 2);

  if (tid < 64) sSq[tid] = 0.f;

  // stage x-hat tile (normalize + bf16), swizzled
  {
    int row = tid >> 2;
    int c0 = (tid & 3) * 64;
    const float* xr = X + (size_t)(gr0 + row) * CC;
    #pragma unroll
    for (int i = 0; i < 8; ++i) {
      int c = c0 + i * 8;
      f32x4 xa = *(const f32x4*)(xr + c);
      f32x4 xb = *(const f32x4*)(xr + c + 4);
      float xv[8] = {xa.x, xa.y, xa.z, xa.w, xb.x, xb.y, xb.z, xb.w};
      bf16x8 hh;
      #pragma unroll
      for (int j = 0; j < 8; ++j) {
        float x = xv[j];
        if (donorm) x = (x - mean[c + j]) * rstd[c + j];
        hh[j] = (short)f2bf(x);
      }
      int jchunk = (tid & 3) * 8 + (i ^ (row & 7));
      *(bf16x8*)(sX + row * 256 + jchunk * 8) = hh;
    }
  }

  f32x4 zero4 = {0.f, 0.f, 0.f, 0.f};
  f32x4 acc[4][4];
  #pragma unroll
  for (int i = 0; i < 4; ++i)
    #pragma unroll
    for (int j = 0; j < 4; ++j) acc[i][j] = zero4;

  int n0 = wid * 64;   // this wave's output-col base
  const unsigned short* wb = Wt + (size_t)z * 65536;

  for (int chn = 0; chn < 4; ++chn) {
    int kk0 = chn * 64;
    __syncthreads();
    // stage W chunk [256 d][64 k], swizzled (8 chunks/row)
    #pragma unroll
    for (int it = 0; it < 8; ++it) {
      int L = it * 256 + wid * 64 + lane;
      int d = L >> 3, s = L & 7;
      int j = s ^ (d & 7);
      async_cp16(wb + d * 256 + kk0 + j * 8,
                 (char*)sWOT + (size_t)(it * 256 + uwid * 64) * 16);
    }
    __syncthreads();
    #pragma unroll
    for (int ks = 0; ks < 2; ++ks) {
      bf16x8 a[4];
      #pragma unroll
      for (int mf = 0; mf < 4; ++mf) {
        int row = mf * 16 + l16;
        int j = chn * 8 + ((ks * 4 + quad) ^ (row & 7));
        a[mf] = *(const bf16x8*)(sX + row * 256 + j * 8);
      }
      #pragma unroll
      for (int nf = 0; nf < 4; ++nf) {
        int d = n0 + nf * 16 + l16;
        int j = (ks * 4 + quad) ^ (d & 7);
        bf16x8 bw = *(const bf16x8*)(sWOT + d * 64 + j * 8);
        #pragma unroll
        for (int mf = 0; mf < 4; ++mf) acc[mf][nf] = MFMA_BF16(a[mf], bw, acc[mf][nf]);
      }
    }
  }

  // bias
  const float* bias = (z == 0) ? bq : ((z == 1) ? bk : bv);
  #pragma unroll
  for (int nf = 0; nf < 4; ++nf) {
    float bb_ = bias[n0 + nf * 16 + l16];
    #pragma unroll
    for (int mf = 0; mf < 4; ++mf) {
      acc[mf][nf].x += bb_; acc[mf][nf].y += bb_;
      acc[mf][nf].z += bb_; acc[mf][nf].w += bb_;
    }
  }

  if (z < 2) {
    // l2-normalize rows, store fp8
    #pragma unroll
    for (int mf = 0; mf < 4; ++mf) {
      f32x4 ss = zero4;
      #pragma unroll
      for (int nf = 0; nf < 4; ++nf) ss += acc[mf][nf] * acc[mf][nf];
      #pragma unroll
      for (int m = 1; m < 16; m <<= 1) {
        ss.x += __shfl_xor(ss.x, m, 64);
        ss.y += __shfl_xor(ss.y, m, 64);
        ss.z += __shfl_xor(ss.z, m, 64);
        ss.w += __shfl_xor(ss.w, m, 64);
      }
      if (l16 == 0) {
        int r0 = mf * 16 + quad * 4;
        atomicAdd(&sSq[r0 + 0], ss.x);
        atomicAdd(&sSq[r0 + 1], ss.y);
        atomicAdd(&sSq[r0 + 2], ss.z);
        atomicAdd(&sSq[r0 + 3], ss.w);
      }
    }
    __syncthreads();
    if (tid < 64) sSq[tid] = rsqrtf(sSq[tid] + 1e-12f);
    __syncthreads();
    unsigned char* O = (z == 0) ? Qn : Kn;
    #pragma unroll
    for (int mf = 0; mf < 4; ++mf) {
      int r0 = mf * 16 + quad * 4;
      float rn0 = sSq[r0], rn1 = sSq[r0 + 1], rn2 = sSq[r0 + 2], rn3 = sSq[r0 + 3];
      #pragma unroll
      for (int nf = 0; nf < 4; ++nf) {
        int col = n0 + nf * 16 + l16;
        u32 p01 = (u32)__builtin_amdgcn_cvt_pk_fp8_f32(acc[mf][nf].x * rn0, acc[mf][nf].y * rn1, 0, false);
        u32 p23 = (u32)__builtin_amdgcn_cvt_pk_fp8_f32(acc[mf][nf].z * rn2, acc[mf][nf].w * rn3, 0, false);
        O[(size_t)(gr0 + r0 + 0) * CC + col] = (unsigned char)(p01 & 0xff);
        O[(size_t)(gr0 + r0 + 1) * CC + col] = (unsigned char)((p01 >> 8) & 0xff);
        O[(size_t)(gr0 + r0 + 2) * CC + col] = (unsigned char)(p23 & 0xff);
        O[(size_t)(gr0 + r0 + 3) * CC + col] = (unsigned char)((p23 >> 8) & 0xff);
      }
    }
  } else {
    // V path: stage transposed [d][row] into sOT (alias sWOT), swizzled, then fp8 global write
    __syncthreads();   // all waves done reading sWOT as sW
    #pragma unroll
    for (int mf = 0; mf < 4; ++mf) {
      int j0 = mf * 2 + (quad >> 1);
      int sub = (quad & 1) * 4;
      #pragma unroll
      for (int nf = 0; nf < 4; ++nf) {
        int col = n0 + nf * 16 + l16;
        bf16x4 pk;
        pk[0] = (short)f2bf(acc[mf][nf].x);
        pk[1] = (short)f2bf(acc[mf][nf].y);
        pk[2] = (short)f2bf(acc[mf][nf].z);
        pk[3] = (short)f2bf(acc[mf][nf].w);
        *(bf16x4*)(sWOT + col * 64 + (j0 ^ (col & 7)) * 8 + sub) = pk;
      }
    }
    __syncthreads();
    int n_in_b = gr0 & (NN - 1);
    unsigned char* vrow  = Vct + ((size_t)(b * 512 + tid)) * NN + n_in_b;
    unsigned char* v2row = Vct + ((size_t)(b * 512 + 256 + tid)) * NN + n_in_b;
    #pragma unroll
    for (int i = 0; i < 4; ++i) {
      float f[16];
      #pragma unroll
      for (int g = 0; g < 2; ++g) {
        bf16x8 hv = *(const bf16x8*)(sWOT + tid * 64 + ((i * 2 + g) ^ (tid & 7)) * 8);
        #pragma unroll
        for (int j = 0; j < 8; ++j) f[g * 8 + j] = bf2f((unsigned short)hv[j]);
      }
      u32x4 v1, v2;
      v1.x = pk4_fp8(f[0], f[1], f[2], f[3]);
      v1.y = pk4_fp8(f[4], f[5], f[6], f[7]);
      v1.z = pk4_fp8(f[8], f[9], f[10], f[11]);
      v1.w = pk4_fp8(f[12], f[13], f[14], f[15]);
      v2.x = pk4_fp8(f[0]*f[0], f[1]*f[1], f[2]*f[2], f[3]*f[3]);
      v2.y = pk4_fp8(f[4]*f[4], f[5]*f[5], f[6]*f[6], f[7]*f[7]);
      v2.z = pk4_fp8(f[8]*f[8], f[9]*f[9], f[10]*f[10], f[11]*f[11]);
      v2.w = pk4_fp8(f[12]*f[12], f[13]*f[13], f[14]*f[14], f[15]*f[15]);
      *(u32x4*)(vrow + i * 16) = v1;
      *(u32x4*)(v2row + i * 16) = v2;
    }
  }
}

// ---------------- flash attention, fp8, 256 threads, 2 blocks/CU ----------------
// q-tile 32. 4 waves: S^T = K.Q^T (C-layout gives 4 consecutive keys/lane ->
// b32 sP writes). sK+sP double-buffered, sV single, 2 raw barriers per kt,
// uniform vmcnt(4). Grid 512 = 2 blocks/CU for cross-block phase overlap.
__global__ __launch_bounds__(256, 2) void flash_kernel(
    const unsigned char* __restrict__ Qn,
    const unsigned char* __restrict__ Kn,
    const unsigned char* __restrict__ Vct,     // [b][512][N] fp8; ch<256: V, ch>=256: V^2
    const float* __restrict__ content,
    const float* __restrict__ stats,
    float* __restrict__ out) {
  // pool: sK 2x16K | sV 32K | sP 2x2K | sL 128B ; epilogue overlays f32 sE2[256][32] at base
  __shared__ __align__(16) char smem[32768 + 32768 + 4096 + 128];
  char* sKb = smem;                       // 2 x 16384
  char* sVb = smem + 65536;               // 32768  (NOTE: placed after sK bufs)
  char* sPb = smem + 32768;               // wait--see layout note below
  // Layout: [0,32K): sK bufs | [32K,36K): sP bufs | [36K,68K): sV | [68K,+128): sL
  sVb = smem + 36864;
  sPb = smem + 32768;
  float* sL = (float*)(smem + 69632);
  float* sE2 = (float*)smem;              // 32 KB epilogue overlay (sK+sP area)

  int tid = threadIdx.x;
  int wid = tid >> 6, lane = tid & 63, quad = lane >> 4, l16 = lane & 15;
  int uwid = __builtin_amdgcn_readfirstlane(wid);

  int id = blockIdx.x;                    // batch b -> XCDs {2b, 2b+1}
  int b = (id >> 1) & 3;
  int tile = ((id >> 3) << 1) | (id & 1); // 0..127
  int q0 = tile * 32;

  // Q B-frags in registers: qf[ng][kf] = Q[q0+ng*16+l16][kf*32+quad*8 ..+7]
  long qf[2][8];
  #pragma unroll
  for (int ng = 0; ng < 2; ++ng) {
    const unsigned char* base = Qn + (((size_t)b * NN + q0 + ng * 16 + l16) << 8);
    #pragma unroll
    for (int kf = 0; kf < 8; ++kf)
      qf[ng][kf] = *(const long*)(base + kf * 32 + quad * 8);
  }
  __builtin_amdgcn_s_waitcnt(WAITCNT(0, 7, 15));   // drain qf: loop vmcnt counts staging only

  if (tid < 32) sL[tid] = 0.f;

  const unsigned char* kbp = Kn + (((size_t)b * NN) << 8);
  const unsigned char* vbp = Vct + ((size_t)b * 512) * NN;

  // K tile [64 key][256 c] fp8 = 16 KB; 16B chunk swizzle: slot = c16 ^ (key&15)
  auto stageK = [&](int k0, int buf) {
    char* dst = sKb + buf * 16384;
    #pragma unroll
    for (int it = 0; it < 4; ++it) {
      int L = it * 256 + wid * 64 + lane;
      int ky = L >> 4;
      int c16 = (L & 15) ^ (ky & 15);
      async_cp16(kbp + (((size_t)(k0 + ky)) << 8) + c16 * 16,
                 dst + (size_t)(it * 256 + uwid * 64) * 16);
    }
  };
  // [V;V2] tile [512 ch][64 key] fp8 = 32 KB; slot16 = c16 ^ ((ch>>1)&3)
  auto stageV = [&](int k0) {
    #pragma unroll
    for (int it = 0; it < 8; ++it) {
      int L = it * 256 + wid * 64 + lane;
      int ch = L >> 2;
      int c16 = (L & 3) ^ ((ch >> 1) & 3);
      async_cp16(vbp + (size_t)ch * NN + k0 + c16 * 16,
                 sVb + (size_t)(it * 256 + uwid * 64) * 16);
    }
  };

  f32x4 zero4 = {0.f, 0.f, 0.f, 0.f};
  f32x4 om[2][8];
  #pragma unroll
  for (int i = 0; i < 2; ++i)
    #pragma unroll
    for (int j = 0; j < 8; ++j) om[i][j] = zero4;
  float Lr[2] = {0.f, 0.f};

  // prologue: K(0), V(0), K(1)  -> 16 insts/wave in flight
  stageK(0, 0);
  stageV(0);
  stageK(64, 1);

  int cwch[2];   // nothing; placeholder to keep compiler happy (unused)
  (void)cwch;

  for (int kt = 0; kt < 64; ++kt) {
    // K(kt), V(kt) landed; allow K(kt+1)'s 4 newest in flight
    __builtin_amdgcn_s_waitcnt(WAITCNT(4, 7, 15));
    __builtin_amdgcn_s_barrier();                      // alpha

    const char* sKc = sKb + (kt & 1) * 16384;
    char* sPc = sPb + (kt & 1) * 2048;

    // ---- S^T = K.Q^T : wave wid owns keys wid*16..+15, all 32 q ----
    f32x4 s0 = zero4, s1 = zero4;
    #pragma unroll
    for (int kf = 0; kf < 8; ++kf) {
      // A = K-frag: row key = wid*16+l16; c chunk = (kf*2+(quad>>1)) ^ l16
      long ak = *(const long*)(sKc + (wid * 16 + l16) * 256 +
                               ((kf * 2 + (quad >> 1)) ^ l16) * 16 + (quad & 1) * 8);
      s0 = MFMA_FP8(ak, qf[0][kf], s0);
      s1 = MFMA_FP8(ak, qf[1][kf], s1);
    }
    // ---- P = exp(S), accumulate L, b32 write to sP[q][key] (8B-chunk swizzle) ----
    #pragma unroll
    for (int ng = 0; ng < 2; ++ng) {
      f32x4 sv = ng ? s1 : s0;
      float p0 = __expf(sv.x), p1 = __expf(sv.y), p2 = __expf(sv.z), p3 = __expf(sv.w);
      Lr[ng] += p0 + p1 + p2 + p3;
      u32 w = pk4_fp8(p0, p1, p2, p3);        // keys wid*16+quad*4+{0..3}
      int q = ng * 16 + l16;
      int chunk8 = wid * 2 + (quad >> 1);
      *(u32*)(sPc + q * 64 + ((chunk8 ^ (q & 7)) * 8) + (quad & 1) * 4) = w;
    }
    // ---- vf reads from sV (ready since alpha); consumed after beta ----
    long vf[2][8];
    #pragma unroll
    for (int ks = 0; ks < 2; ++ks)
      #pragma unroll
      for (int cg = 0; cg < 8; ++cg) {
        int ch = wid * 128 + cg * 16 + l16;
        int slot = (ks * 2 + (quad >> 1)) ^ ((ch >> 1) & 3);
        vf[ks][cg] = *(const long*)(sVb + ch * 64 + slot * 16 + (quad & 1) * 8);
      }
    __builtin_amdgcn_s_waitcnt(WAITCNT(63, 7, 0));     // sP published; sK/sV reads retired
    __builtin_amdgcn_s_barrier();                      // beta

    // stage next tiles (fly during PV MFMA + next S phase)
    stageV(((kt + 1) & 63) * 64);
    stageK(((kt + 2) & 63) * 64, kt & 1);

    // ---- pf reads from sP[kt&1] (published at beta) ----
    long pf[2][2];
    #pragma unroll
    for (int ks = 0; ks < 2; ++ks)
      #pragma unroll
      for (int mq = 0; mq < 2; ++mq) {
        int q = mq * 16 + l16;
        pf[ks][mq] = *(const long*)(sPc + q * 64 + (((ks * 4 + quad) ^ (q & 7)) * 8));
      }
    // ---- O += P @ [V, V^2] ----
    #pragma unroll
    for (int ks = 0; ks < 2; ++ks)
      #pragma unroll
      for (int cg = 0; cg < 8; ++cg)
        #pragma unroll
        for (int mq = 0; mq < 2; ++mq)
          om[mq][cg] = MFMA_FP8(pf[ks][mq], vf[ks][cg], om[mq][cg]);
  }

  // ---- finalize L: reduce over quads (16 keys), then 4 key-group waves via atomics ----
  #pragma unroll
  for (int ng = 0; ng < 2; ++ng) {
    Lr[ng] += __shfl_xor(Lr[ng], 16, 64);
    Lr[ng] += __shfl_xor(Lr[ng], 32, 64);
  }
  if (quad == 0) {
    atomicAdd(&sL[l16], Lr[0]);
    atomicAdd(&sL[16 + l16], Lr[1]);
  }
  // drain dead prefetch DMA + publish sL before overlaying sE2 on sK/sP area
  __builtin_amdgcn_s_waitcnt(WAITCNT(0, 7, 0));
  __builtin_amdgcn_s_barrier();

  // ---- epilogue: waves 2,3 (V^2 chans) dump E2 numerators: sE2[ch 256][q 32] f32 ----
  if (wid >= 2) {
    #pragma unroll
    for (int mq = 0; mq < 2; ++mq)
      #pragma unroll
      for (int cg = 0; cg < 8; ++cg) {
        int ch = (wid - 2) * 128 + cg * 16 + l16;          // 0..255
        int c4 = (mq * 4 + quad) ^ (ch & 7);
        *(f32x4*)(sE2 + ch * 32 + c4 * 4) = om[mq][cg];
      }
  }
  __syncthreads();

  if (wid < 2) {
    const float* meanc = stats + (0 * BB + b) * CC;
    const float* rstdc = stats + (1 * BB + b) * CC;
    float linv[2][4];
    #pragma unroll
    for (int mq = 0; mq < 2; ++mq)
      #pragma unroll
      for (int r = 0; r < 4; ++r)
        linv[mq][r] = 1.0f / sL[mq * 16 + quad * 4 + r];
    #pragma unroll
    for (int cg = 0; cg < 8; ++cg) {
      int ch = wid * 128 + cg * 16 + l16;                  // 0..255
      float mc = meanc[ch], rc = rstdc[ch];
      #pragma unroll
      for (int mq = 0; mq < 2; ++mq) {
        int c4 = (mq * 4 + quad) ^ (ch & 7);
        f32x4 vv = *(const f32x4*)(sE2 + ch * 32 + c4 * 4);
        f32x4 ov = om[mq][cg];
        #pragma unroll
        for (int r = 0; r < 4; ++r) {
          int row = mq * 16 + quad * 4 + r;
          float li = linv[mq][r];
          float ovr = (r == 0) ? ov.x : (r == 1) ? ov.y : (r == 2) ? ov.z : ov.w;
          float vvr = (r == 0) ? vv.x : (r == 1) ? vv.y : (r == 2) ? vv.z : vv.w;
          float M = ovr * li;
          float E2 = vvr * li;
          float S2 = E2 - M * M;
          float S = (S2 > 0.f) ? sqrtf(S2) : 0.f;
          size_t gi = (((size_t)b * NN + q0 + row) << 8) + ch;
          float xh = (content[gi] - mc) * rc;
          out[gi] = S * xh + M;
        }
      }
    }
  }
}

// ---------------- launcher ----------------
extern "C" void kernel_launch(void* const* d_in, const int* in_sizes, int n_in,
                              void* d_out, int out_size, void* d_ws, size_t ws_size,
                              hipStream_t stream) {
  const float* content = (const float*)d_in[0];
  const float* style   = (const float*)d_in[1];
  const float* Wq = (const float*)d_in[2];
  const float* bq = (const float*)d_in[3];
  const float* Wk = (const float*)d_in[4];
  const float* bk = (const float*)d_in[5];
  const float* Wv = (const float*)d_in[6];
  const float* bv = (const float*)d_in[7];
  char* ws = (char*)d_ws;

  float* sums        = (float*)(ws + 0);                 // 16 KB
  float* stats       = (float*)(ws + 16384);             // 16 KB
  unsigned short* Wt = (unsigned short*)(ws + 32768);    // 384 KB
  unsigned char* Qn  = (unsigned char*)(ws + 425984);    // 4 MB fp8
  unsigned char* Kn  = (unsigned char*)(ws + 4620288);   // 4 MB fp8
  unsigned char* Vct = (unsigned char*)(ws + 8814592);   // 8 MB fp8 [b][512][N]
  float* outp = (float*)d_out;

  hipMemsetAsync(d_ws, 0, 16384, stream);
  hipLaunchKernelGGL(transpose_w, dim3(48), dim3(256), 0, stream, Wq, Wk, Wv, Wt);
  hipLaunchKernelGGL(stats_partial, dim3(1024), dim3(256), 0, stream, content, style, sums);
  hipLaunchKernelGGL(stats_finalize, dim3(8), dim3(256), 0, stream, sums, stats);
  hipLaunchKernelGGL(qkv_kernel, dim3(256, 3), dim3(256), 0, stream,
                     content, style, Wt, bq, bk, bv, stats, Qn, Kn, Vct);
  hipLaunchKernelGGL(flash_kernel, dim3(512), dim3(256), 0, stream,
                     Qn, Kn, Vct, content, stats, outp);
}

// Round 6
// 233.483 us; speedup vs baseline: 1.0958x; 1.0958x over previous
//
#include <hip/hip_runtime.h>
#include <cstdint>

#define BB 4
#define NN 4096
#define CC 256

typedef __attribute__((ext_vector_type(8))) short bf16x8;
typedef __attribute__((ext_vector_type(4))) short bf16x4;
typedef __attribute__((ext_vector_type(4))) float f32x4;
typedef unsigned int u32;
typedef __attribute__((ext_vector_type(4))) u32 u32x4;

#define MFMA_FP8(a, b, c)  __builtin_amdgcn_mfma_f32_16x16x32_fp8_fp8((a), (b), (c), 0, 0, 0)

// gfx9 s_waitcnt immediate: vmcnt[3:0]+[15:14], expcnt[6:4], lgkmcnt[11:8]
#define WAITCNT(vm, xp, lgkm) (((vm) & 0xF) | (((vm) >> 4) << 14) | ((xp) << 4) | ((lgkm) << 8))

__device__ __forceinline__ unsigned short f2bf(float f) {
  union { float f; unsigned u; } v; v.f = f;
  unsigned r = v.u + 0x7fffu + ((v.u >> 16) & 1u);
  return (unsigned short)(r >> 16);
}
// pack 4 f32 -> 4 fp8 e4m3 (OCP) in one dword, byte order a,b,c,d
__device__ __forceinline__ u32 pk4_fp8(float a, float b, float c, float d) {
  u32 v = (u32)__builtin_amdgcn_cvt_pk_fp8_f32(a, b, 0, false);
  v = (u32)__builtin_amdgcn_cvt_pk_fp8_f32(c, d, (int)v, true);
  return v;
}
__device__ __forceinline__ unsigned char fp8_1(float a) {
  return (unsigned char)(((u32)__builtin_amdgcn_cvt_pk_fp8_f32(a, a, 0, false)) & 0xff);
}

typedef __attribute__((address_space(3))) unsigned int lds_u32;
typedef __attribute__((address_space(1))) unsigned int glb_u32;

// async global->LDS, 16B per lane; LDS dest = wave-uniform base + lane*16
__device__ __forceinline__ void async_cp16(const void* g, void* l) {
  __builtin_amdgcn_global_load_lds((const glb_u32*)g,
                                   (lds_u32*)(unsigned)(unsigned long long)l,
                                   16, 0, 0);
}

// ---------------- W transpose: Wt8[z][d][c] = fp8(W_z[c][d]) ----------------
__global__ __launch_bounds__(256) void transpose_w(const float* __restrict__ Wq,
                                                   const float* __restrict__ Wk,
                                                   const float* __restrict__ Wv,
                                                   unsigned char* __restrict__ Wt8) {
  __shared__ float sT[64 * 65];
  int blk = blockIdx.x;            // 48 = 3 * 16
  int z = blk / 16, tl = blk % 16;
  int c0 = (tl >> 2) * 64, d0 = (tl & 3) * 64;
  const float* W = (z == 0) ? Wq : ((z == 1) ? Wk : Wv);
  #pragma unroll
  for (int i = 0; i < 16; ++i) {
    int e = i * 256 + threadIdx.x;
    int c = e >> 6, d = e & 63;
    sT[c * 65 + d] = W[(size_t)(c0 + c) * CC + d0 + d];
  }
  __syncthreads();
  #pragma unroll
  for (int i = 0; i < 16; ++i) {
    int e = i * 256 + threadIdx.x;
    int d = e >> 6, c = e & 63;
    Wt8[(size_t)z * 65536 + (size_t)(d0 + d) * CC + c0 + c] = fp8_1(sT[c * 65 + d]);
  }
}

// ---------------- instance-norm stats ----------------
__global__ __launch_bounds__(256) void stats_partial(const float* __restrict__ content,
                                                     const float* __restrict__ style,
                                                     float* __restrict__ sums) {
  int blk = blockIdx.x;                 // 1024 blocks: [t:2][b:4][chunk:128]
  int t = blk >> 9, b = (blk >> 7) & 3, chunk = blk & 127;
  const float* X = t ? style : content;
  int c = threadIdx.x;
  const float* base = X + ((size_t)b * NN + (size_t)chunk * 32) * CC + c;
  float s = 0.f, ss = 0.f;
  #pragma unroll 8
  for (int r = 0; r < 32; ++r) {
    float x = base[(size_t)r * CC];
    s += x; ss += x * x;
  }
  atomicAdd(&sums[((t * 2 + 0) * BB + b) * CC + c], s);
  atomicAdd(&sums[((t * 2 + 1) * BB + b) * CC + c], ss);
}

__global__ __launch_bounds__(256) void stats_finalize(const float* __restrict__ sums,
                                                      float* __restrict__ stats) {
  int i = blockIdx.x * 256 + threadIdx.x;   // 2048 = 2*B*C
  int t = i >> 10, bc = i & 1023;
  float s = sums[(t * 2 + 0) * 1024 + bc];
  float ss = sums[(t * 2 + 1) * 1024 + bc];
  float m = s * (1.0f / NN);
  float var = ss * (1.0f / NN) - m * m;
  stats[(t * 2 + 0) * 1024 + bc] = m;
  stats[(t * 2 + 1) * 1024 + bc] = rsqrtf(var + 1e-5f);
}

// ---------------- QKV v2: fp8 GEMM, 128-row x 256-col tiles, 256 thr, 2 blocks/CU ----------------
__global__ __launch_bounds__(256, 2) void qkv_kernel(
    const float* __restrict__ content, const float* __restrict__ style,
    const unsigned char* __restrict__ Wt8,
    const float* __restrict__ bq, const float* __restrict__ bk, const float* __restrict__ bv,
    const float* __restrict__ stats,
    unsigned char* __restrict__ Qn, unsigned char* __restrict__ Kn,
    unsigned char* __restrict__ Vct) {
  __shared__ __align__(16) char sW[32768];   // [256 d][128 c] fp8, slot8 = c16 ^ (d&7)
  __shared__ __align__(16) char sX[32768];   // [128 r][256 c] fp8, slot16 = c16 ^ (r&15); V-epilogue alias sOT[256][128]

  int tid = threadIdx.x;
  int wid = tid >> 6, lane = tid & 63, quad = lane >> 4, l16 = lane & 15;
  int uwid = __builtin_amdgcn_readfirstlane(wid);
  int tileid = blockIdx.x;      // 0..127 over B*N/128
  int z = blockIdx.y;           // 0=Q 1=K 2=V
  int gr0 = tileid * 128;       // global row over B*N
  int b = gr0 >> 12;

  const float* X = (z == 0) ? content : style;
  int statt = (z == 0) ? 0 : 1;
  const float* mean = stats + ((statt * 2 + 0) * BB + b) * CC;
  const float* rstd = stats + ((statt * 2 + 1) * BB + b) * CC;
  bool donorm = (z < 2);

  // ---- stage sX: x-hat (or raw style for V) quantized to fp8, swizzled ----
  #pragma unroll
  for (int i = 0; i < 8; ++i) {
    int lin = i * 256 + tid;
    int row = lin >> 4, c16 = lin & 15;
    int c = c16 * 16;
    const float* xr = X + (size_t)(gr0 + row) * CC + c;
    f32x4 x0 = *(const f32x4*)(xr + 0);
    f32x4 x1 = *(const f32x4*)(xr + 4);
    f32x4 x2 = *(const f32x4*)(xr + 8);
    f32x4 x3 = *(const f32x4*)(xr + 12);
    if (donorm) {
      f32x4 m0 = *(const f32x4*)(mean + c + 0), r0 = *(const f32x4*)(rstd + c + 0);
      f32x4 m1 = *(const f32x4*)(mean + c + 4), r1 = *(const f32x4*)(rstd + c + 4);
      f32x4 m2 = *(const f32x4*)(mean + c + 8), r2 = *(const f32x4*)(rstd + c + 8);
      f32x4 m3 = *(const f32x4*)(mean + c + 12), r3 = *(const f32x4*)(rstd + c + 12);
      x0 = (x0 - m0) * r0; x1 = (x1 - m1) * r1;
      x2 = (x2 - m2) * r2; x3 = (x3 - m3) * r3;
    }
    u32x4 pk;
    pk.x = pk4_fp8(x0.x, x0.y, x0.z, x0.w);
    pk.y = pk4_fp8(x1.x, x1.y, x1.z, x1.w);
    pk.z = pk4_fp8(x2.x, x2.y, x2.z, x2.w);
    pk.w = pk4_fp8(x3.x, x3.y, x3.z, x3.w);
    *(u32x4*)(sX + row * 256 + ((c16 ^ (row & 15)) * 16)) = pk;
  }

  f32x4 zero4 = {0.f, 0.f, 0.f, 0.f};
  f32x4 acc[2][16];
  #pragma unroll
  for (int i = 0; i < 2; ++i)
    #pragma unroll
    for (int j = 0; j < 16; ++j) acc[i][j] = zero4;

  const unsigned char* wb = Wt8 + (size_t)z * 65536;

  for (int half = 0; half < 2; ++half) {
    __syncthreads();   // sX visible (half0) / sW reads of prior half done (half1)
    // stage sW half: [256 d][128 c] fp8 from Wt8[z][d][half*128+..]
    #pragma unroll
    for (int it = 0; it < 8; ++it) {
      int L = it * 256 + wid * 64 + lane;
      int d = L >> 3;
      int c16 = (L & 7) ^ (d & 7);
      async_cp16(wb + (size_t)d * 256 + half * 128 + c16 * 16,
                 sW + (size_t)(it * 256 + uwid * 64) * 16);
    }
    __syncthreads();   // drain (compiler emits vmcnt(0) before barrier)

    // A-frags: rows wid*32 + mf*16 + l16, k-chunks kc*32 + quad*8 within this half
    long a[2][4];
    #pragma unroll
    for (int mf = 0; mf < 2; ++mf) {
      int row = wid * 32 + mf * 16 + l16;
      #pragma unroll
      for (int kc = 0; kc < 4; ++kc) {
        int chunk = half * 8 + kc * 2 + (quad >> 1);
        a[mf][kc] = *(const long*)(sX + row * 256 + ((chunk ^ (row & 15)) * 16) + (quad & 1) * 8);
      }
    }
    #pragma unroll
    for (int nf = 0; nf < 16; ++nf) {
      int d = nf * 16 + l16;
      #pragma unroll
      for (int kc = 0; kc < 4; ++kc) {
        long bw = *(const long*)(sW + d * 128 + (((kc * 2 + (quad >> 1)) ^ (d & 7)) * 16) + (quad & 1) * 8);
        acc[0][nf] = MFMA_FP8(a[0][kc], bw, acc[0][nf]);
        acc[1][nf] = MFMA_FP8(a[1][kc], bw, acc[1][nf]);
      }
    }
  }

  // ---- bias (before l2norm / store) ----
  const float* bias = (z == 0) ? bq : ((z == 1) ? bk : bv);
  #pragma unroll
  for (int nf = 0; nf < 16; ++nf) {
    float bb_ = bias[nf * 16 + l16];
    #pragma unroll
    for (int mf = 0; mf < 2; ++mf) {
      acc[mf][nf].x += bb_; acc[mf][nf].y += bb_;
      acc[mf][nf].z += bb_; acc[mf][nf].w += bb_;
    }
  }

  if (z < 2) {
    // l2-normalize rows (sum over all 256 cols lives in this wave), store fp8 row-major
    unsigned char* O = (z == 0) ? Qn : Kn;
    #pragma unroll
    for (int mf = 0; mf < 2; ++mf) {
      f32x4 ss = zero4;
      #pragma unroll
      for (int nf = 0; nf < 16; ++nf) ss += acc[mf][nf] * acc[mf][nf];
      #pragma unroll
      for (int m = 1; m < 16; m <<= 1) {
        ss.x += __shfl_xor(ss.x, m, 64);
        ss.y += __shfl_xor(ss.y, m, 64);
        ss.z += __shfl_xor(ss.z, m, 64);
        ss.w += __shfl_xor(ss.w, m, 64);
      }
      f32x4 rq;
      rq.x = rsqrtf(ss.x + 1e-12f); rq.y = rsqrtf(ss.y + 1e-12f);
      rq.z = rsqrtf(ss.z + 1e-12f); rq.w = rsqrtf(ss.w + 1e-12f);
      int r0 = wid * 32 + mf * 16 + quad * 4;
      #pragma unroll
      for (int nf = 0; nf < 16; ++nf) {
        int col = nf * 16 + l16;
        u32 p01 = (u32)__builtin_amdgcn_cvt_pk_fp8_f32(acc[mf][nf].x * rq.x, acc[mf][nf].y * rq.y, 0, false);
        u32 p23 = (u32)__builtin_amdgcn_cvt_pk_fp8_f32(acc[mf][nf].z * rq.z, acc[mf][nf].w * rq.w, 0, false);
        O[(size_t)(gr0 + r0 + 0) * CC + col] = (unsigned char)(p01 & 0xff);
        O[(size_t)(gr0 + r0 + 1) * CC + col] = (unsigned char)((p01 >> 8) & 0xff);
        O[(size_t)(gr0 + r0 + 2) * CC + col] = (unsigned char)(p23 & 0xff);
        O[(size_t)(gr0 + r0 + 3) * CC + col] = (unsigned char)((p23 >> 8) & 0xff);
      }
    }
  } else {
    // V: two passes through sOT (alias sX): pass0 = V, pass1 = V^2; coalesced fp8 writes
    char* sOT = sX;   // [256 ch][128 row] fp8, chunk j' = j ^ (ch&7)
    int n_in_b = gr0 & (NN - 1);
    __syncthreads();   // all sX A-reads done
    #pragma unroll
    for (int pass = 0; pass < 2; ++pass) {
      #pragma unroll
      for (int mf = 0; mf < 2; ++mf) {
        int j = wid * 2 + mf;
        int r4 = wid * 32 + mf * 16 + quad * 4;  // unswizzled byte offset base = j*16 + quad*4
        (void)r4;
        #pragma unroll
        for (int nf = 0; nf < 16; ++nf) {
          int col = nf * 16 + l16;
          f32x4 v = acc[mf][nf];
          f32x4 w = pass ? (v * v) : v;
          u32 pk = pk4_fp8(w.x, w.y, w.z, w.w);
          *(u32*)(sOT + col * 128 + ((j ^ (col & 7)) * 16) + quad * 4) = pk;
        }
      }
      __syncthreads();
      unsigned char* orow = Vct + ((size_t)(b * 512 + (pass ? 256 : 0) + tid)) * NN + n_in_b;
      #pragma unroll
      for (int j = 0; j < 8; ++j) {
        u32x4 val = *(const u32x4*)(sOT + tid * 128 + ((j ^ (tid & 7)) * 16));
        *(u32x4*)(orow + j * 16) = val;
      }
      __syncthreads();
    }
  }
}

// ---------------- flash attention, all-fp8 datapath (R4 structure: 512 thr, q-tile 64) ----------------
__global__ __launch_bounds__(512, 2) void flash_kernel(
    const unsigned char* __restrict__ Qn,
    const unsigned char* __restrict__ Kn,
    const unsigned char* __restrict__ Vct,     // [b][512][N] fp8; ch<256: V, ch>=256: V^2
    const float* __restrict__ content,
    const float* __restrict__ stats,
    float* __restrict__ out) {
  // pool: sK 2x16K | sV 2x32K | sP 4K | sL 256B ; epilogue overlays f32 sE2[256][64] at base
  __shared__ __align__(16) char smem[32768 + 65536 + 4096 + 256];
  char* sKb = smem;
  char* sVb = smem + 32768;
  char* sP  = smem + 98304;
  float* sL = (float*)(smem + 102400);
  float* sE2 = (float*)smem;

  int tid = threadIdx.x;
  int wid = tid >> 6, lane = tid & 63, quad = lane >> 4, l16 = lane & 15;
  int uwid = __builtin_amdgcn_readfirstlane(wid);

  int id = blockIdx.x;                       // XCD swizzle: batch b on XCDs {2b,2b+1}
  int b = (id >> 1) & 3;
  int tile = ((id >> 3) << 1) | (id & 1);
  int q0 = tile * 64;

  int qh = (wid & 1) * 32;         // S-phase q base (32 rows)
  int kb0 = (wid >> 1) * 16;       // S-phase key base (16 keys)
  int cw = wid * 64;               // PV ch base (64 of 512)

  // Q A-frags fp8 in registers: rows q0+qh+{0,16}+l16, full C=256
  long qf[2][8];
  #pragma unroll
  for (int mf = 0; mf < 2; ++mf) {
    int row = q0 + qh + mf * 16 + l16;
    const unsigned char* base = Qn + (((size_t)b * NN + row) << 8);
    #pragma unroll
    for (int kf = 0; kf < 8; ++kf)
      qf[mf][kf] = *(const long*)(base + kf * 32 + quad * 8);
  }
  __builtin_amdgcn_s_waitcnt(WAITCNT(0, 7, 15));   // drain qf: loop vmcnt counts staging only

  if (tid < 64) sL[tid] = 0.f;

  const unsigned char* kbp = Kn + (((size_t)b * NN) << 8);
  const unsigned char* vbp = Vct + ((size_t)b * 512) * NN;

  // K tile [64 key][256 c] fp8 = 16 KB; 16B chunks swizzled: slot = c16 ^ (key&15)
  auto stageK = [&](int k0, int buf) {
    char* dst = sKb + buf * 16384;
    #pragma unroll
    for (int it = 0; it < 2; ++it) {
      int L = it * 512 + wid * 64 + lane;
      int ky = L >> 4, s = L & 15;
      int c16 = s ^ (ky & 15);
      async_cp16(kbp + (((size_t)(k0 + ky)) << 8) + c16 * 16,
                 dst + (size_t)(it * 512 + uwid * 64) * 16);
    }
  };
  // [V;V2] tile [512 ch][64 key] fp8 = 32 KB; 128B row-pairs, slot8 = ((ch&1)*4+c16) ^ ((ch>>1)&7)
  auto stageV = [&](int k0, int buf) {
    char* dst = sVb + buf * 32768;
    #pragma unroll
    for (int it = 0; it < 4; ++it) {
      int L = it * 512 + wid * 64 + lane;
      int r128 = L >> 3, s8 = L & 7;
      int x = s8 ^ (r128 & 7);
      int ch = (r128 << 1) | (x >> 2);
      int k16 = x & 3;
      async_cp16(vbp + (size_t)ch * NN + k0 + k16 * 16,
                 dst + (size_t)(it * 512 + uwid * 64) * 16);
    }
  };

  f32x4 zero4 = {0.f, 0.f, 0.f, 0.f};
  f32x4 om[4][4];
  #pragma unroll
  for (int i = 0; i < 4; ++i)
    #pragma unroll
    for (int j = 0; j < 4; ++j) om[i][j] = zero4;
  float Lr[8];
  #pragma unroll
  for (int i = 0; i < 8; ++i) Lr[i] = 0.f;

  // prologue: tiles 0 and 1 (6 loads each)
  stageK(0, 0);  stageV(0, 0);
  stageK(64, 1); stageV(64, 1);

  int keyrow = (kb0 + l16) * 256;
  int key15 = l16;                  // (kb0+l16)&15
  int khalf = (quad & 1) * 8;

  for (int kt = 0; kt < 64; ++kt) {
    // tile kt ready (6 newer = tile kt+1 in flight)
    __builtin_amdgcn_s_waitcnt(WAITCNT(6, 7, 15));
    __builtin_amdgcn_s_barrier();

    const char* sKc = sKb + (kt & 1) * 16384;
    // ---- S = Q.K^T : wave computes D[q 32][key 16], fp8 MFMA ----
    f32x4 s0 = zero4, s1 = zero4;
    #pragma unroll
    for (int kf = 0; kf < 8; ++kf) {
      int slot = (kf * 2 + (quad >> 1)) ^ key15;
      long bk = *(const long*)(sKc + keyrow + slot * 16 + khalf);
      s0 = MFMA_FP8(qf[0][kf], bk, s0);
      s1 = MFMA_FP8(qf[1][kf], bk, s1);
    }
    // ---- P = exp(S), accumulate L, fp8 scatter to sP ----
    #pragma unroll
    for (int mf = 0; mf < 2; ++mf) {
      f32x4 sv = mf ? s1 : s0;
      float p0 = __expf(sv.x), p1 = __expf(sv.y), p2 = __expf(sv.z), p3 = __expf(sv.w);
      Lr[mf * 4 + 0] += p0; Lr[mf * 4 + 1] += p1;
      Lr[mf * 4 + 2] += p2; Lr[mf * 4 + 3] += p3;
      u32 b01 = (u32)__builtin_amdgcn_cvt_pk_fp8_f32(p0, p1, 0, false);
      u32 b23 = (u32)__builtin_amdgcn_cvt_pk_fp8_f32(p2, p3, 0, false);
      int qbase = qh + mf * 16 + quad * 4;
      #pragma unroll
      for (int r = 0; r < 4; ++r) {
        int q = qbase + r;
        u32 byte = (r < 2) ? ((r == 0) ? (b01 & 0xff) : ((b01 >> 8) & 0xff))
                           : ((r == 2) ? (b23 & 0xff) : ((b23 >> 8) & 0xff));
        int addr = (q >> 1) * 128 + ((((q & 1) * 4 + (wid >> 1))) ^ ((q >> 1) & 7)) * 16 + l16;
        sP[addr] = (unsigned char)byte;
      }
    }
    __builtin_amdgcn_s_waitcnt(WAITCNT(63, 7, 0));   // sP visible; own sK reads retired
    __builtin_amdgcn_s_barrier();

    // ---- prefetch PV fragments (fp8) to registers ----
    const char* sVc = sVb + (kt & 1) * 32768;
    long pf[2][4], vf[2][4];
    #pragma unroll
    for (int ks = 0; ks < 2; ++ks) {
      int c16 = ks * 2 + (quad >> 1);
      #pragma unroll
      for (int mf2 = 0; mf2 < 4; ++mf2) {
        int q = mf2 * 16 + l16;
        pf[ks][mf2] = *(const long*)(sP + (q >> 1) * 128 +
                        (((q & 1) * 4 + c16) ^ ((q >> 1) & 7)) * 16 + khalf);
      }
      #pragma unroll
      for (int nf = 0; nf < 4; ++nf) {
        int ch = cw + nf * 16 + l16;
        vf[ks][nf] = *(const long*)(sVc + (ch >> 1) * 128 +
                        (((ch & 1) * 4 + c16) ^ ((ch >> 1) & 7)) * 16 + khalf);
      }
    }
    __builtin_amdgcn_s_waitcnt(WAITCNT(63, 7, 0));   // all own LDS reads retired
    __builtin_amdgcn_s_barrier();                    // -> everyone's reads done, bufs reusable

    int nk = ((kt + 2) & 63) * 64;   // wrapped (kt>=62 refetches tiles 0/1: harmless)
    stageK(nk, kt & 1);
    stageV(nk, kt & 1);

    // ---- O += P @ [V, V^2] from registers ----
    #pragma unroll
    for (int ks = 0; ks < 2; ++ks)
      #pragma unroll
      for (int nf = 0; nf < 4; ++nf)
        #pragma unroll
        for (int mf2 = 0; mf2 < 4; ++mf2)
          om[mf2][nf] = MFMA_FP8(pf[ks][mf2], vf[ks][nf], om[mf2][nf]);
  }

  // ---- finalize L: sum over keys (l16 lanes), then over the 4 kb-waves ----
  #pragma unroll
  for (int i = 0; i < 8; ++i) {
    #pragma unroll
    for (int m = 1; m < 16; m <<= 1) Lr[i] += __shfl_xor(Lr[i], m, 64);
  }
  if (l16 == 0) {
    #pragma unroll
    for (int mf = 0; mf < 2; ++mf)
      #pragma unroll
      for (int r = 0; r < 4; ++r)
        atomicAdd(&sL[qh + mf * 16 + quad * 4 + r], Lr[mf * 4 + r]);
  }
  // drain dead prefetch DMA + make sL visible before overlaying sE2 on sK/sV
  __builtin_amdgcn_s_waitcnt(WAITCNT(0, 7, 0));
  __builtin_amdgcn_s_barrier();

  // ---- epilogue: waves 4..7 dump E2 numerators to LDS (f32 [256][64], 16-chunk swizzle) ----
  if (wid >= 4) {
    #pragma unroll
    for (int mf2 = 0; mf2 < 4; ++mf2) {
      #pragma unroll
      for (int nf = 0; nf < 4; ++nf) {
        int ch = (wid - 4) * 64 + nf * 16 + l16;
        int cidx = (mf2 * 4 + quad) ^ (ch & 15);
        *(f32x4*)(sE2 + ch * 64 + cidx * 4) = om[mf2][nf];
      }
    }
  }
  __syncthreads();

  if (wid < 4) {
    const float* meanc = stats + (0 * BB + b) * CC;     // content mean
    const float* rstdc = stats + (1 * BB + b) * CC;     // content rstd
    float linv[4][4];
    #pragma unroll
    for (int mf2 = 0; mf2 < 4; ++mf2)
      #pragma unroll
      for (int r = 0; r < 4; ++r)
        linv[mf2][r] = 1.0f / sL[mf2 * 16 + quad * 4 + r];
    #pragma unroll
    for (int nf = 0; nf < 4; ++nf) {
      int ch = cw + nf * 16 + l16;     // 0..255
      float mc = meanc[ch], rc = rstdc[ch];
      #pragma unroll
      for (int mf2 = 0; mf2 < 4; ++mf2) {
        int cidx = (mf2 * 4 + quad) ^ (ch & 15);
        f32x4 vv = *(const f32x4*)(sE2 + ch * 64 + cidx * 4);
        f32x4 ov = om[mf2][nf];
        #pragma unroll
        for (int r = 0; r < 4; ++r) {
          int row = mf2 * 16 + quad * 4 + r;
          float li = linv[mf2][r];
          float ovr = (r == 0) ? ov.x : (r == 1) ? ov.y : (r == 2) ? ov.z : ov.w;
          float vvr = (r == 0) ? vv.x : (r == 1) ? vv.y : (r == 2) ? vv.z : vv.w;
          float M = ovr * li;
          float E2 = vvr * li;
          float S2 = E2 - M * M;
          float S = (S2 > 0.f) ? sqrtf(S2) : 0.f;
          size_t gi = (((size_t)b * NN + q0 + row) << 8) + ch;
          float xh = (content[gi] - mc) * rc;
          out[gi] = S * xh + M;
        }
      }
    }
  }
}

// ---------------- launcher ----------------
extern "C" void kernel_launch(void* const* d_in, const int* in_sizes, int n_in,
                              void* d_out, int out_size, void* d_ws, size_t ws_size,
                              hipStream_t stream) {
  const float* content = (const float*)d_in[0];
  const float* style   = (const float*)d_in[1];
  const float* Wq = (const float*)d_in[2];
  const float* bq = (const float*)d_in[3];
  const float* Wk = (const float*)d_in[4];
  const float* bk = (const float*)d_in[5];
  const float* Wv = (const float*)d_in[6];
  const float* bv = (const float*)d_in[7];
  char* ws = (char*)d_ws;

  float* sums        = (float*)(ws + 0);                 // 16 KB
  float* stats       = (float*)(ws + 16384);             // 16 KB
  unsigned char* Wt8 = (unsigned char*)(ws + 32768);     // 192 KB fp8 [3][256][256]
  unsigned char* Qn  = (unsigned char*)(ws + 229376);    // 4 MB fp8
  unsigned char* Kn  = (unsigned char*)(ws + 4423680);   // 4 MB fp8
  unsigned char* Vct = (unsigned char*)(ws + 8617984);   // 8 MB fp8 [b][512][N]
  float* outp = (float*)d_out;

  hipMemsetAsync(d_ws, 0, 16384, stream);
  hipLaunchKernelGGL(transpose_w, dim3(48), dim3(256), 0, stream, Wq, Wk, Wv, Wt8);
  hipLaunchKernelGGL(stats_partial, dim3(1024), dim3(256), 0, stream, content, style, sums);
  hipLaunchKernelGGL(stats_finalize, dim3(8), dim3(256), 0, stream, sums, stats);
  hipLaunchKernelGGL(qkv_kernel, dim3(128, 3), dim3(256), 0, stream,
                     content, style, Wt8, bq, bk, bv, stats, Qn, Kn, Vct);
  hipLaunchKernelGGL(flash_kernel, dim3(256), dim3(512), 0, stream,
                     Qn, Kn, Vct, content, stats, outp);
}

// Round 7
// 207.352 us; speedup vs baseline: 1.2338x; 1.1260x over previous
//
#include <hip/hip_runtime.h>
#include <cstdint>

#define BB 4
#define NN 4096
#define CC 256

typedef __attribute__((ext_vector_type(8))) short bf16x8;
typedef __attribute__((ext_vector_type(4))) short bf16x4;
typedef __attribute__((ext_vector_type(4))) float f32x4;
typedef unsigned int u32;
typedef __attribute__((ext_vector_type(4))) u32 u32x4;

#define MFMA_FP8(a, b, c)  __builtin_amdgcn_mfma_f32_16x16x32_fp8_fp8((a), (b), (c), 0, 0, 0)

// gfx9 s_waitcnt immediate: vmcnt[3:0]+[15:14], expcnt[6:4], lgkmcnt[11:8]
#define WAITCNT(vm, xp, lgkm) (((vm) & 0xF) | (((vm) >> 4) << 14) | ((xp) << 4) | ((lgkm) << 8))

__device__ __forceinline__ unsigned short f2bf(float f) {
  union { float f; unsigned u; } v; v.f = f;
  unsigned r = v.u + 0x7fffu + ((v.u >> 16) & 1u);
  return (unsigned short)(r >> 16);
}
// pack 4 f32 -> 4 fp8 e4m3 (OCP) in one dword, byte order a,b,c,d
__device__ __forceinline__ u32 pk4_fp8(float a, float b, float c, float d) {
  u32 v = (u32)__builtin_amdgcn_cvt_pk_fp8_f32(a, b, 0, false);
  v = (u32)__builtin_amdgcn_cvt_pk_fp8_f32(c, d, (int)v, true);
  return v;
}
__device__ __forceinline__ unsigned char fp8_1(float a) {
  return (unsigned char)(((u32)__builtin_amdgcn_cvt_pk_fp8_f32(a, a, 0, false)) & 0xff);
}

typedef __attribute__((address_space(3))) unsigned int lds_u32;
typedef __attribute__((address_space(1))) unsigned int glb_u32;

// async global->LDS, 16B per lane; LDS dest = wave-uniform base + lane*16
__device__ __forceinline__ void async_cp16(const void* g, void* l) {
  __builtin_amdgcn_global_load_lds((const glb_u32*)g,
                                   (lds_u32*)(unsigned)(unsigned long long)l,
                                   16, 0, 0);
}

// ---------------- W transpose: Wt8[z][d][c] = fp8(W_z[c][d]) ----------------
__global__ __launch_bounds__(256) void transpose_w(const float* __restrict__ Wq,
                                                   const float* __restrict__ Wk,
                                                   const float* __restrict__ Wv,
                                                   unsigned char* __restrict__ Wt8) {
  __shared__ float sT[64 * 65];
  int blk = blockIdx.x;            // 48 = 3 * 16
  int z = blk / 16, tl = blk % 16;
  int c0 = (tl >> 2) * 64, d0 = (tl & 3) * 64;
  const float* W = (z == 0) ? Wq : ((z == 1) ? Wk : Wv);
  #pragma unroll
  for (int i = 0; i < 16; ++i) {
    int e = i * 256 + threadIdx.x;
    int c = e >> 6, d = e & 63;
    sT[c * 65 + d] = W[(size_t)(c0 + c) * CC + d0 + d];
  }
  __syncthreads();
  #pragma unroll
  for (int i = 0; i < 16; ++i) {
    int e = i * 256 + threadIdx.x;
    int d = e >> 6, c = e & 63;
    Wt8[(size_t)z * 65536 + (size_t)(d0 + d) * CC + c0 + c] = fp8_1(sT[c * 65 + d]);
  }
}

// ---------------- instance-norm stats ----------------
__global__ __launch_bounds__(256) void stats_partial(const float* __restrict__ content,
                                                     const float* __restrict__ style,
                                                     float* __restrict__ sums) {
  int blk = blockIdx.x;                 // 1024 blocks: [t:2][b:4][chunk:128]
  int t = blk >> 9, b = (blk >> 7) & 3, chunk = blk & 127;
  const float* X = t ? style : content;
  int c = threadIdx.x;
  const float* base = X + ((size_t)b * NN + (size_t)chunk * 32) * CC + c;
  float s = 0.f, ss = 0.f;
  #pragma unroll 8
  for (int r = 0; r < 32; ++r) {
    float x = base[(size_t)r * CC];
    s += x; ss += x * x;
  }
  atomicAdd(&sums[((t * 2 + 0) * BB + b) * CC + c], s);
  atomicAdd(&sums[((t * 2 + 1) * BB + b) * CC + c], ss);
}

__global__ __launch_bounds__(256) void stats_finalize(const float* __restrict__ sums,
                                                      float* __restrict__ stats) {
  int i = blockIdx.x * 256 + threadIdx.x;   // 2048 = 2*B*C
  int t = i >> 10, bc = i & 1023;
  float s = sums[(t * 2 + 0) * 1024 + bc];
  float ss = sums[(t * 2 + 1) * 1024 + bc];
  float m = s * (1.0f / NN);
  float var = ss * (1.0f / NN) - m * m;
  stats[(t * 2 + 0) * 1024 + bc] = m;
  stats[(t * 2 + 1) * 1024 + bc] = rsqrtf(var + 1e-5f);
}

// ---------------- QKV v2: fp8 GEMM, 128-row x 256-col tiles, 256 thr, 2 blocks/CU ----------------
__global__ __launch_bounds__(256, 2) void qkv_kernel(
    const float* __restrict__ content, const float* __restrict__ style,
    const unsigned char* __restrict__ Wt8,
    const float* __restrict__ bq, const float* __restrict__ bk, const float* __restrict__ bv,
    const float* __restrict__ stats,
    unsigned char* __restrict__ Qn, unsigned char* __restrict__ Kn,
    unsigned char* __restrict__ Vct) {
  __shared__ __align__(16) char sW[32768];   // [256 d][128 c] fp8, slot8 = c16 ^ (d&7)
  __shared__ __align__(16) char sX[32768];   // [128 r][256 c] fp8, slot16 = c16 ^ (r&15); V-epilogue alias sOT[256][128]

  int tid = threadIdx.x;
  int wid = tid >> 6, lane = tid & 63, quad = lane >> 4, l16 = lane & 15;
  int uwid = __builtin_amdgcn_readfirstlane(wid);
  int tileid = blockIdx.x;      // 0..127 over B*N/128
  int z = blockIdx.y;           // 0=Q 1=K 2=V
  int gr0 = tileid * 128;       // global row over B*N
  int b = gr0 >> 12;

  const float* X = (z == 0) ? content : style;
  int statt = (z == 0) ? 0 : 1;
  const float* mean = stats + ((statt * 2 + 0) * BB + b) * CC;
  const float* rstd = stats + ((statt * 2 + 1) * BB + b) * CC;
  bool donorm = (z < 2);

  // ---- stage sX: x-hat (or raw style for V) quantized to fp8, swizzled ----
  #pragma unroll
  for (int i = 0; i < 8; ++i) {
    int lin = i * 256 + tid;
    int row = lin >> 4, c16 = lin & 15;
    int c = c16 * 16;
    const float* xr = X + (size_t)(gr0 + row) * CC + c;
    f32x4 x0 = *(const f32x4*)(xr + 0);
    f32x4 x1 = *(const f32x4*)(xr + 4);
    f32x4 x2 = *(const f32x4*)(xr + 8);
    f32x4 x3 = *(const f32x4*)(xr + 12);
    if (donorm) {
      f32x4 m0 = *(const f32x4*)(mean + c + 0), r0 = *(const f32x4*)(rstd + c + 0);
      f32x4 m1 = *(const f32x4*)(mean + c + 4), r1 = *(const f32x4*)(rstd + c + 4);
      f32x4 m2 = *(const f32x4*)(mean + c + 8), r2 = *(const f32x4*)(rstd + c + 8);
      f32x4 m3 = *(const f32x4*)(mean + c + 12), r3 = *(const f32x4*)(rstd + c + 12);
      x0 = (x0 - m0) * r0; x1 = (x1 - m1) * r1;
      x2 = (x2 - m2) * r2; x3 = (x3 - m3) * r3;
    }
    u32x4 pk;
    pk.x = pk4_fp8(x0.x, x0.y, x0.z, x0.w);
    pk.y = pk4_fp8(x1.x, x1.y, x1.z, x1.w);
    pk.z = pk4_fp8(x2.x, x2.y, x2.z, x2.w);
    pk.w = pk4_fp8(x3.x, x3.y, x3.z, x3.w);
    *(u32x4*)(sX + row * 256 + ((c16 ^ (row & 15)) * 16)) = pk;
  }

  f32x4 zero4 = {0.f, 0.f, 0.f, 0.f};
  f32x4 acc[2][16];
  #pragma unroll
  for (int i = 0; i < 2; ++i)
    #pragma unroll
    for (int j = 0; j < 16; ++j) acc[i][j] = zero4;

  const unsigned char* wb = Wt8 + (size_t)z * 65536;

  for (int half = 0; half < 2; ++half) {
    __syncthreads();   // sX visible (half0) / sW reads of prior half done (half1)
    // stage sW half: [256 d][128 c] fp8 from Wt8[z][d][half*128+..]
    #pragma unroll
    for (int it = 0; it < 8; ++it) {
      int L = it * 256 + wid * 64 + lane;
      int d = L >> 3;
      int c16 = (L & 7) ^ (d & 7);
      async_cp16(wb + (size_t)d * 256 + half * 128 + c16 * 16,
                 sW + (size_t)(it * 256 + uwid * 64) * 16);
    }
    __syncthreads();   // drain (compiler emits vmcnt(0) before barrier)

    // A-frags: rows wid*32 + mf*16 + l16, k-chunks kc*32 + quad*8 within this half
    long a[2][4];
    #pragma unroll
    for (int mf = 0; mf < 2; ++mf) {
      int row = wid * 32 + mf * 16 + l16;
      #pragma unroll
      for (int kc = 0; kc < 4; ++kc) {
        int chunk = half * 8 + kc * 2 + (quad >> 1);
        a[mf][kc] = *(const long*)(sX + row * 256 + ((chunk ^ (row & 15)) * 16) + (quad & 1) * 8);
      }
    }
    #pragma unroll
    for (int nf = 0; nf < 16; ++nf) {
      int d = nf * 16 + l16;
      #pragma unroll
      for (int kc = 0; kc < 4; ++kc) {
        long bw = *(const long*)(sW + d * 128 + (((kc * 2 + (quad >> 1)) ^ (d & 7)) * 16) + (quad & 1) * 8);
        acc[0][nf] = MFMA_FP8(a[0][kc], bw, acc[0][nf]);
        acc[1][nf] = MFMA_FP8(a[1][kc], bw, acc[1][nf]);
      }
    }
  }

  // ---- bias (before l2norm / store) ----
  const float* bias = (z == 0) ? bq : ((z == 1) ? bk : bv);
  #pragma unroll
  for (int nf = 0; nf < 16; ++nf) {
    float bb_ = bias[nf * 16 + l16];
    #pragma unroll
    for (int mf = 0; mf < 2; ++mf) {
      acc[mf][nf].x += bb_; acc[mf][nf].y += bb_;
      acc[mf][nf].z += bb_; acc[mf][nf].w += bb_;
    }
  }

  if (z < 2) {
    // l2-normalize rows (sum over all 256 cols lives in this wave), store fp8 row-major
    unsigned char* O = (z == 0) ? Qn : Kn;
    #pragma unroll
    for (int mf = 0; mf < 2; ++mf) {
      f32x4 ss = zero4;
      #pragma unroll
      for (int nf = 0; nf < 16; ++nf) ss += acc[mf][nf] * acc[mf][nf];
      #pragma unroll
      for (int m = 1; m < 16; m <<= 1) {
        ss.x += __shfl_xor(ss.x, m, 64);
        ss.y += __shfl_xor(ss.y, m, 64);
        ss.z += __shfl_xor(ss.z, m, 64);
        ss.w += __shfl_xor(ss.w, m, 64);
      }
      f32x4 rq;
      rq.x = rsqrtf(ss.x + 1e-12f); rq.y = rsqrtf(ss.y + 1e-12f);
      rq.z = rsqrtf(ss.z + 1e-12f); rq.w = rsqrtf(ss.w + 1e-12f);
      int r0 = wid * 32 + mf * 16 + quad * 4;
      #pragma unroll
      for (int nf = 0; nf < 16; ++nf) {
        int col = nf * 16 + l16;
        u32 p01 = (u32)__builtin_amdgcn_cvt_pk_fp8_f32(acc[mf][nf].x * rq.x, acc[mf][nf].y * rq.y, 0, false);
        u32 p23 = (u32)__builtin_amdgcn_cvt_pk_fp8_f32(acc[mf][nf].z * rq.z, acc[mf][nf].w * rq.w, 0, false);
        O[(size_t)(gr0 + r0 + 0) * CC + col] = (unsigned char)(p01 & 0xff);
        O[(size_t)(gr0 + r0 + 1) * CC + col] = (unsigned char)((p01 >> 8) & 0xff);
        O[(size_t)(gr0 + r0 + 2) * CC + col] = (unsigned char)(p23 & 0xff);
        O[(size_t)(gr0 + r0 + 3) * CC + col] = (unsigned char)((p23 >> 8) & 0xff);
      }
    }
  } else {
    // V: two passes through sOT (alias sX): pass0 = V, pass1 = V^2; coalesced fp8 writes
    char* sOT = sX;   // [256 ch][128 row] fp8, chunk j' = j ^ (ch&7)
    int n_in_b = gr0 & (NN - 1);
    __syncthreads();   // all sX A-reads done
    #pragma unroll
    for (int pass = 0; pass < 2; ++pass) {
      #pragma unroll
      for (int mf = 0; mf < 2; ++mf) {
        int j = wid * 2 + mf;
        #pragma unroll
        for (int nf = 0; nf < 16; ++nf) {
          int col = nf * 16 + l16;
          f32x4 v = acc[mf][nf];
          f32x4 w = pass ? (v * v) : v;
          u32 pk = pk4_fp8(w.x, w.y, w.z, w.w);
          *(u32*)(sOT + col * 128 + ((j ^ (col & 7)) * 16) + quad * 4) = pk;
        }
      }
      __syncthreads();
      unsigned char* orow = Vct + ((size_t)(b * 512 + (pass ? 256 : 0) + tid)) * NN + n_in_b;
      #pragma unroll
      for (int j = 0; j < 8; ++j) {
        u32x4 val = *(const u32x4*)(sOT + tid * 128 + ((j ^ (tid & 7)) * 16));
        *(u32x4*)(orow + j * 16) = val;
      }
      __syncthreads();
    }
  }
}

// ---------------- flash attention, fp8, single-barrier pipelined K-loop ----------------
// 512 thr (8 waves), q-tile 64. S^T = K.Q^T so P exits with 4 consecutive keys
// per lane -> conflict-free b32 sP writes. Per kt: stage(kt+2) | pf(kt) | PV(kt)
// | wait vmcnt(6) | S(kt+1)+exp+vf(kt+1)+sP(kt+1) | lgkm wait | ONE s_barrier.
__global__ __launch_bounds__(512, 2) void flash_kernel(
    const unsigned char* __restrict__ Qn,
    const unsigned char* __restrict__ Kn,
    const unsigned char* __restrict__ Vct,     // [b][512][N] fp8; ch<256: V, ch>=256: V^2
    const float* __restrict__ content,
    const float* __restrict__ stats,
    float* __restrict__ out) {
  // layout: sK 2x16K | sV 2x32K | sP 2x4K | sL 256B; epilogue overlays f32 sE2[256][64]
  __shared__ __align__(16) char smem[32768 + 65536 + 8192 + 256];
  char* sKb = smem;
  char* sVb = smem + 32768;
  char* sPb = smem + 98304;
  float* sL = (float*)(smem + 106496);
  float* sE2 = (float*)smem;

  int tid = threadIdx.x;
  int wid = tid >> 6, lane = tid & 63, quad = lane >> 4, l16 = lane & 15;
  int uwid = __builtin_amdgcn_readfirstlane(wid);

  int id = blockIdx.x;                       // XCD swizzle: batch b on XCDs {2b,2b+1}
  int b = (id >> 1) & 3;
  int tile = ((id >> 3) << 1) | (id & 1);
  int q0 = tile * 64;

  int qh = (wid & 1) * 32;         // S-phase q base (32 q per wave)
  int kb0 = (wid >> 1) * 16;       // S-phase key stripe (16 keys)
  int cw = wid * 64;               // PV ch base (64 of 512)

  // Q B-frags fp8 in registers: lane holds Q[q = qh+ng*16+l16][k = kf*32+quad*8..+7]
  long qf[2][8];
  #pragma unroll
  for (int ng = 0; ng < 2; ++ng) {
    int row = q0 + qh + ng * 16 + l16;
    const unsigned char* base = Qn + (((size_t)b * NN + row) << 8);
    #pragma unroll
    for (int kf = 0; kf < 8; ++kf)
      qf[ng][kf] = *(const long*)(base + kf * 32 + quad * 8);
  }
  __builtin_amdgcn_s_waitcnt(WAITCNT(0, 7, 15));   // drain qf: loop vmcnt counts staging only

  if (tid < 64) sL[tid] = 0.f;

  const unsigned char* kbp = Kn + (((size_t)b * NN) << 8);
  const unsigned char* vbp = Vct + ((size_t)b * 512) * NN;

  // K tile [64 key][256 c] fp8 = 16 KB; 16B chunks swizzled: slot = c16 ^ (key&15)
  auto stageK = [&](int k0, int buf) {
    char* dst = sKb + buf * 16384;
    #pragma unroll
    for (int it = 0; it < 2; ++it) {
      int L = it * 512 + wid * 64 + lane;
      int ky = L >> 4, s = L & 15;
      int c16 = s ^ (ky & 15);
      async_cp16(kbp + (((size_t)(k0 + ky)) << 8) + c16 * 16,
                 dst + (size_t)(it * 512 + uwid * 64) * 16);
    }
  };
  // [V;V2] tile [512 ch][64 key] fp8 = 32 KB; 128B row-pairs, slot8 = ((ch&1)*4+c16) ^ ((ch>>1)&7)
  auto stageV = [&](int k0, int buf) {
    char* dst = sVb + buf * 32768;
    #pragma unroll
    for (int it = 0; it < 4; ++it) {
      int L = it * 512 + wid * 64 + lane;
      int r128 = L >> 3, s8 = L & 7;
      int x = s8 ^ (r128 & 7);
      int ch = (r128 << 1) | (x >> 2);
      int k16 = x & 3;
      async_cp16(vbp + (size_t)ch * NN + k0 + k16 * 16,
                 dst + (size_t)(it * 512 + uwid * 64) * 16);
    }
  };

  f32x4 zero4 = {0.f, 0.f, 0.f, 0.f};
  f32x4 om[4][4];
  #pragma unroll
  for (int i = 0; i < 4; ++i)
    #pragma unroll
    for (int j = 0; j < 4; ++j) om[i][j] = zero4;
  float Lr[2] = {0.f, 0.f};
  long vf[2][4];    // V fragments for current kt, loaded pre-barrier

  int krow = kb0 + l16;
  int krowoff = krow * 256;
  int khalf = (quad & 1) * 8;

  // S^T(kt) + exp + sP(kt) write + vf(kt) register loads
  auto s_phase = [&](int kt) {
    const char* sKc = sKb + (kt & 1) * 16384;
    char* sPc = sPb + (kt & 1) * 4096;
    f32x4 t0 = zero4, t1 = zero4;
    #pragma unroll
    for (int kf = 0; kf < 8; ++kf) {
      int slot = (kf * 2 + (quad >> 1)) ^ (krow & 15);
      long ak = *(const long*)(sKc + krowoff + slot * 16 + khalf);
      t0 = MFMA_FP8(ak, qf[0][kf], t0);     // D[key][q], keys quad*4+reg, q=l16
      t1 = MFMA_FP8(ak, qf[1][kf], t1);
    }
    #pragma unroll
    for (int ng = 0; ng < 2; ++ng) {
      f32x4 sv = ng ? t1 : t0;
      float p0 = __expf(sv.x), p1 = __expf(sv.y), p2 = __expf(sv.z), p3 = __expf(sv.w);
      Lr[ng] += p0 + p1 + p2 + p3;          // sum over this lane's 4 keys for q
      u32 w = pk4_fp8(p0, p1, p2, p3);      // bytes = keys (kb0+quad*4)+0..3
      int q = qh + ng * 16 + l16;
      int c = (kb0 >> 2) + quad;            // 4B-chunk = key/4
      *(u32*)(sPc + q * 64 + ((c ^ (q & 14)) * 4)) = w;
    }
    const char* sVc = sVb + (kt & 1) * 32768;
    #pragma unroll
    for (int ks = 0; ks < 2; ++ks) {
      int c16 = ks * 2 + (quad >> 1);
      #pragma unroll
      for (int nf = 0; nf < 4; ++nf) {
        int ch = cw + nf * 16 + l16;
        vf[ks][nf] = *(const long*)(sVc + (ch >> 1) * 128 +
                        (((ch & 1) * 4 + c16) ^ ((ch >> 1) & 7)) * 16 + khalf);
      }
    }
  };

  // prologue: tiles 0,1 in flight; S(0)+vf(0)+sP(0); publish
  stageK(0, 0);  stageV(0, 0);
  stageK(64, 1); stageV(64, 1);
  __builtin_amdgcn_s_waitcnt(WAITCNT(6, 7, 15));   // tile 0 landed
  __builtin_amdgcn_s_barrier();
  s_phase(0);
  __builtin_amdgcn_s_waitcnt(WAITCNT(63, 7, 0));   // sP(0) + own LDS reads done
  __builtin_amdgcn_s_barrier();

  for (int kt = 0; kt < 64; ++kt) {
    // stage kt+2 into bufs (kt&1): sK read by S(kt) pre-beta, sV read by vf(kt) pre-beta
    int nk = ((kt + 2) & 63) * 64;   // wrap: dead prefetch on last iters, drained in epilogue
    stageK(nk, kt & 1);
    stageV(nk, kt & 1);

    // pf(kt) from sP[kt&1] (published at previous barrier); b64, conflict-free
    const char* sPc = sPb + (kt & 1) * 4096;
    long pf[2][4];
    #pragma unroll
    for (int ks = 0; ks < 2; ++ks)
      #pragma unroll
      for (int mf = 0; mf < 4; ++mf) {
        int q = mf * 16 + l16;
        int c = ks * 8 + quad * 2;
        pf[ks][mf] = *(const long*)(sPc + q * 64 + ((c ^ (q & 14)) * 4));
      }

    // O += P @ [V, V^2] (vf registers loaded last segment)
    #pragma unroll
    for (int ks = 0; ks < 2; ++ks)
      #pragma unroll
      for (int nf = 0; nf < 4; ++nf)
        #pragma unroll
        for (int mf = 0; mf < 4; ++mf)
          om[mf][nf] = MFMA_FP8(pf[ks][mf], vf[ks][nf], om[mf][nf]);

    // tile kt+1 landed (6 newest = kt+2's staging)
    __builtin_amdgcn_s_waitcnt(WAITCNT(6, 7, 15));
    if (kt < 63) s_phase(kt + 1);

    __builtin_amdgcn_s_waitcnt(WAITCNT(63, 7, 0));   // sP(kt+1) visible; all own LDS reads retired
    __builtin_amdgcn_s_barrier();                    // the ONE barrier per kt
  }

  // ---- finalize L: Lr[ng] holds per-(q=l16) sums over this wave's 16-key stripe x all kt,
  //      split across quads; reduce quads then combine 4 key-stripe waves via atomics ----
  #pragma unroll
  for (int ng = 0; ng < 2; ++ng) {
    Lr[ng] += __shfl_xor(Lr[ng], 16, 64);
    Lr[ng] += __shfl_xor(Lr[ng], 32, 64);
  }
  if (quad == 0) {
    atomicAdd(&sL[qh + 0 + l16], Lr[0]);
    atomicAdd(&sL[qh + 16 + l16], Lr[1]);
  }
  // drain dead prefetch DMA + publish sL before overlaying sE2 on sK/sV
  __builtin_amdgcn_s_waitcnt(WAITCNT(0, 7, 0));
  __builtin_amdgcn_s_barrier();

  // ---- epilogue: waves 4..7 dump E2 numerators to LDS (f32 [256][64], 16-chunk swizzle) ----
  if (wid >= 4) {
    #pragma unroll
    for (int mf = 0; mf < 4; ++mf) {
      #pragma unroll
      for (int nf = 0; nf < 4; ++nf) {
        int ch = (wid - 4) * 64 + nf * 16 + l16;
        int cidx = (mf * 4 + quad) ^ (ch & 15);
        *(f32x4*)(sE2 + ch * 64 + cidx * 4) = om[mf][nf];
      }
    }
  }
  __syncthreads();

  if (wid < 4) {
    const float* meanc = stats + (0 * BB + b) * CC;     // content mean
    const float* rstdc = stats + (1 * BB + b) * CC;     // content rstd
    float linv[4][4];
    #pragma unroll
    for (int mf = 0; mf < 4; ++mf)
      #pragma unroll
      for (int r = 0; r < 4; ++r)
        linv[mf][r] = 1.0f / sL[mf * 16 + quad * 4 + r];
    #pragma unroll
    for (int nf = 0; nf < 4; ++nf) {
      int ch = cw + nf * 16 + l16;     // 0..255
      float mc = meanc[ch], rc = rstdc[ch];
      #pragma unroll
      for (int mf = 0; mf < 4; ++mf) {
        int cidx = (mf * 4 + quad) ^ (ch & 15);
        f32x4 vv = *(const f32x4*)(sE2 + ch * 64 + cidx * 4);
        f32x4 ov = om[mf][nf];
        #pragma unroll
        for (int r = 0; r < 4; ++r) {
          int row = mf * 16 + quad * 4 + r;
          float li = linv[mf][r];
          float ovr = (r == 0) ? ov.x : (r == 1) ? ov.y : (r == 2) ? ov.z : ov.w;
          float vvr = (r == 0) ? vv.x : (r == 1) ? vv.y : (r == 2) ? vv.z : vv.w;
          float M = ovr * li;
          float E2 = vvr * li;
          float S2 = E2 - M * M;
          float S = (S2 > 0.f) ? sqrtf(S2) : 0.f;
          size_t gi = (((size_t)b * NN + q0 + row) << 8) + ch;
          float xh = (content[gi] - mc) * rc;
          out[gi] = S * xh + M;
        }
      }
    }
  }
}

// ---------------- launcher ----------------
extern "C" void kernel_launch(void* const* d_in, const int* in_sizes, int n_in,
                              void* d_out, int out_size, void* d_ws, size_t ws_size,
                              hipStream_t stream) {
  const float* content = (const float*)d_in[0];
  const float* style   = (const float*)d_in[1];
  const float* Wq = (const float*)d_in[2];
  const float* bq = (const float*)d_in[3];
  const float* Wk = (const float*)d_in[4];
  const float* bk = (const float*)d_in[5];
  const float* Wv = (const float*)d_in[6];
  const float* bv = (const float*)d_in[7];
  char* ws = (char*)d_ws;

  float* sums        = (float*)(ws + 0);                 // 16 KB
  float* stats       = (float*)(ws + 16384);             // 16 KB
  unsigned char* Wt8 = (unsigned char*)(ws + 32768);     // 192 KB fp8 [3][256][256]
  unsigned char* Qn  = (unsigned char*)(ws + 229376);    // 4 MB fp8
  unsigned char* Kn  = (unsigned char*)(ws + 4423680);   // 4 MB fp8
  unsigned char* Vct = (unsigned char*)(ws + 8617984);   // 8 MB fp8 [b][512][N]
  float* outp = (float*)d_out;

  hipMemsetAsync(d_ws, 0, 16384, stream);
  hipLaunchKernelGGL(transpose_w, dim3(48), dim3(256), 0, stream, Wq, Wk, Wv, Wt8);
  hipLaunchKernelGGL(stats_partial, dim3(1024), dim3(256), 0, stream, content, style, sums);
  hipLaunchKernelGGL(stats_finalize, dim3(8), dim3(256), 0, stream, sums, stats);
  hipLaunchKernelGGL(qkv_kernel, dim3(128, 3), dim3(256), 0, stream,
                     content, style, Wt8, bq, bk, bv, stats, Qn, Kn, Vct);
  hipLaunchKernelGGL(flash_kernel, dim3(256), dim3(512), 0, stream,
                     Qn, Kn, Vct, content, stats, outp);
}